// Round 9
// baseline (467.125 us; speedup 1.0000x reference)
//
#include <hip/hip_runtime.h>

// LGCN encoder. bf16 propagated embeddings, fp32 acc (= d_out).
// SpMM: one wave per row, 8 lanes x 16B (8 bf16) per gather, 16 nnz in flight.
// CSR build (no O(nnz) global atomics, no single-block serialization):
//   bucket_count -> scan_buckets -> bucket_bin (coarse, coalesced runs) ->
//   row_qhist (4 blocks/bucket, LDS hist) -> global 2-level scan -> ptr ->
//   bucket_scatter4 (4 blocks/bucket, LDS cursors from ptr+qcnt prefix).
// Streaming reads use nontemporal loads to avoid polluting L2.

constexpr int USER_NUM = 50000;
constexpr int ITEM_NUM = 50000;
constexpr int N_NODES  = USER_NUM + ITEM_NUM;   // 100000
constexpr int EMB      = 64;
constexpr int N_LAYERS = 3;
constexpr int TOTAL    = N_NODES * EMB;         // 6,400,000
constexpr int TOTAL4   = TOTAL / 4;
constexpr int U4       = USER_NUM * EMB / 4;

constexpr int RSHIFT = 11;                      // 2048 rows per bucket
constexpr int RB     = 1 << RSHIFT;
constexpr int KA = (N_NODES + RB - 1) / RB;     // 49
constexpr int KS = (USER_NUM + RB - 1) / RB;    // 25
constexpr int BCHUNK = 2048;
constexpr int CCH    = 4096;

typedef int v2i __attribute__((ext_vector_type(2)));
typedef int v4i __attribute__((ext_vector_type(4)));

__device__ __forceinline__ int   ntl(const int* p)   { return __builtin_nontemporal_load(p); }
__device__ __forceinline__ float ntlf(const float* p){ return __builtin_nontemporal_load(p); }
__device__ __forceinline__ int2  ntl2(const int2* p) {
    v2i v = __builtin_nontemporal_load((const v2i*)p);
    int2 r; r.x = v.x; r.y = v.y; return r;
}

__device__ __forceinline__ unsigned f2bf(float f) {
    unsigned b = __float_as_uint(f);
    return (b + 0x7fffu + ((b >> 16) & 1u)) >> 16;   // RNE
}
__device__ __forceinline__ void bf2x(unsigned u, float& a, float& b) {
    a = __uint_as_float(u << 16);
    b = __uint_as_float(u & 0xffff0000u);
}

__global__ void init_kernel(const float* __restrict__ user_emb,
                            const float* __restrict__ item_emb,
                            unsigned* __restrict__ ego2,
                            float* __restrict__ acc) {
    int i = blockIdx.x * blockDim.x + threadIdx.x;
    if (i >= TOTAL4) return;
    float4 v = (i < U4) ? reinterpret_cast<const float4*>(user_emb)[i]
                        : reinterpret_cast<const float4*>(item_emb)[i - U4];
    reinterpret_cast<float4*>(acc)[i] = v;
    uint2 o;
    o.x = f2bf(v.x) | (f2bf(v.y) << 16);
    o.y = f2bf(v.z) | (f2bf(v.w) << 16);
    reinterpret_cast<uint2*>(ego2)[i] = o;
}

__global__ void zero_small(int* __restrict__ bcntA, int* __restrict__ bcntS) {
    if (threadIdx.x < 64) { bcntA[threadIdx.x] = 0; bcntS[threadIdx.x] = 0; }
}

__global__ void __launch_bounds__(256) bucket_count(
    const int* __restrict__ arows, int annz, int nchA, int* __restrict__ bcntA,
    const int* __restrict__ srows, int snnz, int* __restrict__ bcntS)
{
    __shared__ int h[64];
    const int* rows; int nnz; int* bcnt; int chunk;
    if ((int)blockIdx.x < nchA) { rows = arows; nnz = annz; bcnt = bcntA; chunk = blockIdx.x; }
    else                        { rows = srows; nnz = snnz; bcnt = bcntS; chunk = blockIdx.x - nchA; }
    int t = threadIdx.x;
    if (t < 64) h[t] = 0;
    __syncthreads();
    int beg = chunk * CCH;
    int end = beg + CCH; if (end > nnz) end = nnz;
    for (int idx = beg + t; idx < end; idx += 256)
        atomicAdd(&h[ntl(rows + idx) >> RSHIFT], 1);
    __syncthreads();
    if (t < 64 && h[t] > 0) atomicAdd(&bcnt[t], h[t]);
}

__global__ void scan_buckets(const int* __restrict__ bcntA, int* __restrict__ bbaseA,
                             int* __restrict__ tailA, int* __restrict__ ptrA,
                             const int* __restrict__ bcntS, int* __restrict__ bbaseS,
                             int* __restrict__ tailS, int* __restrict__ ptrS)
{
    __shared__ int bufA[KA + 1], bufS[KS + 1];
    int t = threadIdx.x;
    if (t < KA) bufA[t] = bcntA[t];
    if (t < KS) bufS[t] = bcntS[t];
    __syncthreads();
    if (t == 0) {
        int run = 0;
        for (int i = 0; i < KA; ++i) { int c = bufA[i]; bufA[i] = run; run += c; }
        bufA[KA] = run;
        run = 0;
        for (int i = 0; i < KS; ++i) { int c = bufS[i]; bufS[i] = run; run += c; }
        bufS[KS] = run;
    }
    __syncthreads();
    if (t <= KA) { bbaseA[t] = bufA[t]; if (t < KA) tailA[t] = bufA[t]; }
    if (t <= KS) { bbaseS[t] = bufS[t]; if (t < KS) tailS[t] = bufS[t]; }
    if (t == 0) { ptrA[N_NODES] = bufA[KA]; ptrS[USER_NUM] = bufS[KS]; }
}

__global__ void __launch_bounds__(256) bucket_bin(
    const int* __restrict__ arows, const int* __restrict__ acols,
    const float* __restrict__ avals, int annz, int nchA, int* __restrict__ tailA,
    int* __restrict__ auxRA, int* __restrict__ auxCA, float* __restrict__ auxVA,
    const int* __restrict__ srows, const int* __restrict__ scols,
    const float* __restrict__ svals, int snnz, int* __restrict__ tailS,
    int* __restrict__ auxRS, int* __restrict__ auxCS, float* __restrict__ auxVS)
{
    __shared__ int hcnt[64], hoff[64], hcur[64], hbase[64];
    __shared__ int sR[BCHUNK], sC[BCHUNK];
    __shared__ float sV[BCHUNK];
    const int* rows; const int* cols; const float* vals; int nnz; int* tail;
    int* auxR; int* auxC; float* auxV; int chunk;
    if ((int)blockIdx.x < nchA) {
        rows = arows; cols = acols; vals = avals; nnz = annz; tail = tailA;
        auxR = auxRA; auxC = auxCA; auxV = auxVA; chunk = blockIdx.x;
    } else {
        rows = srows; cols = scols; vals = svals; nnz = snnz; tail = tailS;
        auxR = auxRS; auxC = auxCS; auxV = auxVS; chunk = blockIdx.x - nchA;
    }
    int begE = chunk * BCHUNK;
    int cnt = nnz - begE; if (cnt > BCHUNK) cnt = BCHUNK;
    int t = threadIdx.x;
    if (t < 64) hcnt[t] = 0;
    __syncthreads();
    int r[8], c[8]; float v[8];
    for (int k = 0; k < 8; ++k) {
        int idx = t + k * 256;
        if (idx < cnt) {
            int e = begE + idx;
            r[k] = ntl(rows + e); c[k] = ntl(cols + e); v[k] = ntlf(vals + e);
            atomicAdd(&hcnt[r[k] >> RSHIFT], 1);
        }
    }
    __syncthreads();
    if (t == 0) {
        int run = 0;
        for (int b = 0; b < 64; ++b) { hoff[b] = run; hcur[b] = run; run += hcnt[b]; }
    }
    __syncthreads();
    for (int k = 0; k < 8; ++k) {
        int idx = t + k * 256;
        if (idx < cnt) {
            int b = r[k] >> RSHIFT;
            int pos = atomicAdd(&hcur[b], 1);
            sR[pos] = r[k]; sC[pos] = c[k]; sV[pos] = v[k];
        }
    }
    __syncthreads();
    if (t < 64 && hcnt[t] > 0) hbase[t] = atomicAdd(&tail[t], hcnt[t]);
    __syncthreads();
    for (int idx = t; idx < cnt; idx += 256) {
        int b = sR[idx] >> RSHIFT;
        int g = hbase[b] + (idx - hoff[b]);
        auxR[g] = sR[idx]; auxC[g] = sC[idx]; auxV[g] = sV[idx];
    }
}

// 4 blocks per bucket: histogram one quarter of the bucket's aux segment.
__global__ void __launch_bounds__(1024) row_qhist(
    const int* __restrict__ auxRA, const int* __restrict__ bbaseA, int* __restrict__ qcntA,
    const int* __restrict__ auxRS, const int* __restrict__ bbaseS, int* __restrict__ qcntS)
{
    __shared__ int cur[RB];
    const int* auxR; const int* bbase; int* qcnt; int b, q, K;
    int id = blockIdx.x;
    if (id < 4 * KA) { auxR = auxRA; bbase = bbaseA; qcnt = qcntA; b = id >> 2; q = id & 3; K = KA; }
    else { id -= 4 * KA; auxR = auxRS; bbase = bbaseS; qcnt = qcntS; b = id >> 2; q = id & 3; K = KS; }
    int rowbase = b << RSHIFT;
    int segb = bbase[b], len = bbase[b + 1] - segb;
    int qb = segb + ((len * q) >> 2);
    int qe = segb + ((len * (q + 1)) >> 2);
    int t = threadIdx.x;
    cur[t] = 0; cur[t + 1024] = 0;
    __syncthreads();
    for (int idx = qb + t; idx < qe; idx += 1024)
        atomicAdd(&cur[ntl(auxR + idx) - rowbase], 1);
    __syncthreads();
    int* dst = qcnt + q * (K << RSHIFT) + rowbase;
    dst[t] = cur[t]; dst[t + 1024] = cur[t + 1024];
}

// Two-level scan over cnt[i] = sum_q qcnt[q][i] -> exclusive prefix in ptr[].
__global__ void scan_local2(const int* __restrict__ qcntA, int* __restrict__ ptrA,
                            int* __restrict__ bsumA, int nA, int nbA,
                            const int* __restrict__ qcntS, int* __restrict__ ptrS,
                            int* __restrict__ bsumS, int nS, int strideA, int strideS) {
    __shared__ int buf[1024];
    const int* qcnt; int* ptr; int* bsum; int n; int b; int stride;
    if ((int)blockIdx.x < nbA) { qcnt = qcntA; ptr = ptrA; bsum = bsumA; n = nA; b = blockIdx.x; stride = strideA; }
    else                       { qcnt = qcntS; ptr = ptrS; bsum = bsumS; n = nS; b = blockIdx.x - nbA; stride = strideS; }
    int i = b * 1024 + (int)threadIdx.x;
    int v = 0;
    if (i < n) v = qcnt[i] + qcnt[stride + i] + qcnt[2 * stride + i] + qcnt[3 * stride + i];
    buf[threadIdx.x] = v;
    __syncthreads();
    for (int off = 1; off < 1024; off <<= 1) {
        int t = (threadIdx.x >= (unsigned)off) ? buf[threadIdx.x - off] : 0;
        __syncthreads();
        buf[threadIdx.x] += t;
        __syncthreads();
    }
    if (i < n) ptr[i] = buf[threadIdx.x] - v;
    if (threadIdx.x == 1023) bsum[b] = buf[1023];
}

__global__ void scan_bsums2(int* __restrict__ bsumA, int* __restrict__ ptrA, int nbA, int nA,
                            int* __restrict__ bsumS, int* __restrict__ ptrS, int nbS, int nS) {
    __shared__ int buf[1024];
    int* bsum; int* ptr; int nb; int n;
    if (blockIdx.x == 0) { bsum = bsumA; ptr = ptrA; nb = nbA; n = nA; }
    else                 { bsum = bsumS; ptr = ptrS; nb = nbS; n = nS; }
    int v = ((int)threadIdx.x < nb) ? bsum[threadIdx.x] : 0;
    buf[threadIdx.x] = v;
    __syncthreads();
    for (int off = 1; off < 1024; off <<= 1) {
        int t = (threadIdx.x >= (unsigned)off) ? buf[threadIdx.x - off] : 0;
        __syncthreads();
        buf[threadIdx.x] += t;
        __syncthreads();
    }
    if ((int)threadIdx.x < nb) bsum[threadIdx.x] = buf[threadIdx.x] - v;
    if (threadIdx.x == 1023) ptr[n] = buf[1023];
}

__global__ void add_offsets2(int* __restrict__ ptrA, const int* __restrict__ bsumA, int nA,
                             int* __restrict__ ptrS, const int* __restrict__ bsumS, int nS) {
    int i = blockIdx.x * blockDim.x + threadIdx.x;
    if (i < nA) ptrA[i] += bsumA[i >> 10];
    if (i < nS) ptrS[i] += bsumS[i >> 10];
}

// 4 blocks per bucket: scatter one quarter; cursors = ptr + prefix of qcnt.
__global__ void __launch_bounds__(1024) bucket_scatter4(
    const int* __restrict__ auxRA, const int* __restrict__ auxCA,
    const float* __restrict__ auxVA, const int* __restrict__ bbaseA,
    const int* __restrict__ qcntA, const int* __restrict__ ptrA, int2* __restrict__ packA,
    const int* __restrict__ auxRS, const int* __restrict__ auxCS,
    const float* __restrict__ auxVS, const int* __restrict__ bbaseS,
    const int* __restrict__ qcntS, const int* __restrict__ ptrS, int2* __restrict__ packS)
{
    __shared__ int cur[RB];
    const int* auxR; const int* auxC; const float* auxV; const int* bbase;
    const int* qcnt; const int* ptr; int2* pack; int b, q, K, n;
    int id = blockIdx.x;
    if (id < 4 * KA) {
        auxR = auxRA; auxC = auxCA; auxV = auxVA; bbase = bbaseA;
        qcnt = qcntA; ptr = ptrA; pack = packA; b = id >> 2; q = id & 3; K = KA; n = N_NODES;
    } else {
        id -= 4 * KA;
        auxR = auxRS; auxC = auxCS; auxV = auxVS; bbase = bbaseS;
        qcnt = qcntS; ptr = ptrS; pack = packS; b = id >> 2; q = id & 3; K = KS; n = USER_NUM;
    }
    int rowbase = b << RSHIFT;
    int nrows = n - rowbase; if (nrows > RB) nrows = RB;
    int segb = bbase[b], len = bbase[b + 1] - segb;
    int qb = segb + ((len * q) >> 2);
    int qe = segb + ((len * (q + 1)) >> 2);
    int t = threadIdx.x;
    int stride = K << RSHIFT;
    for (int i = t; i < nrows; i += 1024) {
        int c = ptr[rowbase + i];
        for (int qq = 0; qq < q; ++qq) c += qcnt[qq * stride + rowbase + i];
        cur[i] = c;
    }
    __syncthreads();
    for (int idx = qb + t; idx < qe; idx += 1024) {
        int r = ntl(auxR + idx);
        int pos = atomicAdd(&cur[r - rowbase], 1);
        pack[pos] = make_int2(ntl(auxC + idx), __float_as_int(ntlf(auxV + idx)));
    }
}

__device__ __forceinline__ void gacc(float (&acc)[8], float v, uint4 u) {
    float f0, f1, f2, f3, f4, f5, f6, f7;
    bf2x(u.x, f0, f1); bf2x(u.y, f2, f3); bf2x(u.z, f4, f5); bf2x(u.w, f6, f7);
    acc[0] += v * f0; acc[1] += v * f1; acc[2] += v * f2; acc[3] += v * f3;
    acc[4] += v * f4; acc[5] += v * f5; acc[6] += v * f6; acc[7] += v * f7;
}
__device__ __forceinline__ void reduce8(float (&acc)[8]) {
    for (int m = 8; m < 64; m <<= 1)
        for (int k = 0; k < 8; ++k)
            acc[k] += __shfl_xor(acc[k], m, 64);
}
__device__ __forceinline__ uint4 pack8(const float (&acc)[8]) {
    uint4 o;
    o.x = f2bf(acc[0]) | (f2bf(acc[1]) << 16);
    o.y = f2bf(acc[2]) | (f2bf(acc[3]) << 16);
    o.z = f2bf(acc[4]) | (f2bf(acc[5]) << 16);
    o.w = f2bf(acc[6]) | (f2bf(acc[7]) << 16);
    return o;
}

__global__ void spmm_s(const int* __restrict__ ptr, const int2* __restrict__ pack,
                       const uint4* __restrict__ ego8, uint4* __restrict__ hu8) {
    int r = blockIdx.x * (blockDim.x >> 6) + (threadIdx.x >> 6);
    if (r >= USER_NUM) return;
    int lane = threadIdx.x & 63;
    int g = lane >> 3, li = lane & 7;
    int beg = ptr[r], end = ptr[r + 1];
    float acc[8] = {0, 0, 0, 0, 0, 0, 0, 0};
    int j = beg + g;
    for (; j + 8 < end; j += 16) {
        int2 p0 = ntl2(pack + j);
        int2 p1 = ntl2(pack + j + 8);
        uint4 x0 = ego8[p0.x * 8 + li];
        uint4 x1 = ego8[p1.x * 8 + li];
        gacc(acc, __int_as_float(p0.y), x0);
        gacc(acc, __int_as_float(p1.y), x1);
    }
    if (j < end) {
        int2 p = ntl2(pack + j);
        gacc(acc, __int_as_float(p.y), ego8[p.x * 8 + li]);
    }
    reduce8(acc);
    if (g == 0) {
        uint4 e = ego8[r * 8 + li];
        float f0, f1;
        bf2x(e.x, f0, f1); acc[0] += f0; acc[1] += f1;
        bf2x(e.y, f0, f1); acc[2] += f0; acc[3] += f1;
        bf2x(e.z, f0, f1); acc[4] += f0; acc[5] += f1;
        bf2x(e.w, f0, f1); acc[6] += f0; acc[7] += f1;
        hu8[r * 8 + li] = pack8(acc);
    }
}

__global__ void spmm_adj(const int* __restrict__ ptr, const int2* __restrict__ pack,
                         const uint4* __restrict__ hu8, const uint4* __restrict__ ego8,
                         uint4* __restrict__ next8, float* __restrict__ accbuf, int last) {
    int r = blockIdx.x * (blockDim.x >> 6) + (threadIdx.x >> 6);
    if (r >= N_NODES) return;
    int lane = threadIdx.x & 63;
    int g = lane >> 3, li = lane & 7;
    int beg = ptr[r], end = ptr[r + 1];
    float acc[8] = {0, 0, 0, 0, 0, 0, 0, 0};
    int j = beg + g;
    for (; j + 8 < end; j += 16) {
        int2 p0 = ntl2(pack + j);
        int2 p1 = ntl2(pack + j + 8);
        uint4 x0 = (p0.x < USER_NUM) ? hu8[p0.x * 8 + li] : ego8[p0.x * 8 + li];
        uint4 x1 = (p1.x < USER_NUM) ? hu8[p1.x * 8 + li] : ego8[p1.x * 8 + li];
        gacc(acc, __int_as_float(p0.y), x0);
        gacc(acc, __int_as_float(p1.y), x1);
    }
    if (j < end) {
        int2 p = ntl2(pack + j);
        uint4 x = (p.x < USER_NUM) ? hu8[p.x * 8 + li] : ego8[p.x * 8 + li];
        gacc(acc, __int_as_float(p.y), x);
    }
    reduce8(acc);
    if (g == 0) {
        if (!last) next8[r * 8 + li] = pack8(acc);
        float4* acc4 = reinterpret_cast<float4*>(accbuf);
        int base = r * 16 + li * 2;
        float4 a0 = acc4[base], a1 = acc4[base + 1];
        a0.x += acc[0]; a0.y += acc[1]; a0.z += acc[2]; a0.w += acc[3];
        a1.x += acc[4]; a1.y += acc[5]; a1.z += acc[6]; a1.w += acc[7];
        if (last) {
            a0.x *= 0.25f; a0.y *= 0.25f; a0.z *= 0.25f; a0.w *= 0.25f;
            a1.x *= 0.25f; a1.y *= 0.25f; a1.z *= 0.25f; a1.w *= 0.25f;
        }
        acc4[base] = a0; acc4[base + 1] = a1;
    }
}

extern "C" void kernel_launch(void* const* d_in, const int* in_sizes, int n_in,
                              void* d_out, int out_size, void* d_ws, size_t ws_size,
                              hipStream_t stream) {
    const float* user_emb = (const float*)d_in[0];
    const float* item_emb = (const float*)d_in[1];
    const int*   adj_rows = (const int*)d_in[2];
    const int*   adj_cols = (const int*)d_in[3];
    const float* adj_vals = (const float*)d_in[4];
    const int*   s_rows   = (const int*)d_in[5];
    const int*   s_cols   = (const int*)d_in[6];
    const float* s_vals   = (const float*)d_in[7];
    const int adj_nnz = in_sizes[2];
    const int s_nnz   = in_sizes[5];

    float* acc = (float*)d_out;

    char* p = (char*)d_ws;
    auto alloc = [&](size_t bytes) { void* q = p; p += (bytes + 255) & ~(size_t)255; return q; };
    unsigned* egoA = (unsigned*)alloc((size_t)TOTAL * 2);
    unsigned* egoB = (unsigned*)alloc((size_t)TOTAL * 2);
    unsigned* hu   = (unsigned*)alloc((size_t)USER_NUM * EMB * 2);
    int*   ptrA  = (int*)alloc((size_t)(N_NODES + 1) * 4);
    int2*  packA = (int2*)alloc((size_t)adj_nnz * 8);
    int*   ptrS  = (int*)alloc((size_t)(USER_NUM + 1) * 4);
    int2*  packS = (int2*)alloc((size_t)s_nnz * 8);
    int*   auxRA = (int*)alloc((size_t)adj_nnz * 4);
    int*   auxCA = (int*)alloc((size_t)adj_nnz * 4);
    float* auxVA = (float*)alloc((size_t)adj_nnz * 4);
    int*   auxRS = (int*)alloc((size_t)s_nnz * 4);
    int*   auxCS = (int*)alloc((size_t)s_nnz * 4);
    float* auxVS = (float*)alloc((size_t)s_nnz * 4);
    int*   qcntA = (int*)alloc((size_t)4 * KA * RB * 4);
    int*   qcntS = (int*)alloc((size_t)4 * KS * RB * 4);
    int*   bcntA = (int*)alloc(64 * 4);
    int*   bcntS = (int*)alloc(64 * 4);
    int*   bbaseA= (int*)alloc(64 * 4);
    int*   bbaseS= (int*)alloc(64 * 4);
    int*   tailA = (int*)alloc(64 * 4);
    int*   tailS = (int*)alloc(64 * 4);
    int*   bsumA = (int*)alloc(1024 * 4);
    int*   bsumS = (int*)alloc(1024 * 4);

    const int BLK = 256;
    const int ew_grid = (TOTAL4 + BLK - 1) / BLK;
    const int nchA = (adj_nnz + BCHUNK - 1) / BCHUNK;
    const int nchS = (s_nnz + BCHUNK - 1) / BCHUNK;
    const int nccA = (adj_nnz + CCH - 1) / CCH;
    const int nccS = (s_nnz + CCH - 1) / CCH;
    const int nbA = (N_NODES + 1023) / 1024;   // 98
    const int nbS = (USER_NUM + 1023) / 1024;  // 49

    // ---- CSR build ----
    zero_small<<<1, 64, 0, stream>>>(bcntA, bcntS);
    bucket_count<<<nccA + nccS, 256, 0, stream>>>(adj_rows, adj_nnz, nccA, bcntA,
                                                  s_rows, s_nnz, bcntS);
    scan_buckets<<<1, 64, 0, stream>>>(bcntA, bbaseA, tailA, ptrA,
                                       bcntS, bbaseS, tailS, ptrS);
    bucket_bin<<<nchA + nchS, 256, 0, stream>>>(
        adj_rows, adj_cols, adj_vals, adj_nnz, nchA, tailA, auxRA, auxCA, auxVA,
        s_rows, s_cols, s_vals, s_nnz, tailS, auxRS, auxCS, auxVS);
    row_qhist<<<4 * (KA + KS), 1024, 0, stream>>>(auxRA, bbaseA, qcntA,
                                                  auxRS, bbaseS, qcntS);
    scan_local2<<<nbA + nbS, 1024, 0, stream>>>(qcntA, ptrA, bsumA, N_NODES, nbA,
                                                qcntS, ptrS, bsumS, USER_NUM,
                                                KA << RSHIFT, KS << RSHIFT);
    scan_bsums2<<<2, 1024, 0, stream>>>(bsumA, ptrA, nbA, N_NODES,
                                        bsumS, ptrS, nbS, USER_NUM);
    add_offsets2<<<(N_NODES + BLK - 1) / BLK, BLK, 0, stream>>>(ptrA, bsumA, N_NODES,
                                                                ptrS, bsumS, USER_NUM);
    bucket_scatter4<<<4 * (KA + KS), 1024, 0, stream>>>(
        auxRA, auxCA, auxVA, bbaseA, qcntA, ptrA, packA,
        auxRS, auxCS, auxVS, bbaseS, qcntS, ptrS, packS);

    // ---- init ----
    init_kernel<<<ew_grid, BLK, 0, stream>>>(user_emb, item_emb, egoA, acc);

    unsigned* ego  = egoA;
    unsigned* next = egoB;
    const int s_grid   = (USER_NUM + 3) / 4;
    const int adj_grid = (N_NODES + 3) / 4;

    for (int l = 0; l < N_LAYERS; ++l) {
        spmm_s<<<s_grid, BLK, 0, stream>>>(ptrS, packS, (const uint4*)ego, (uint4*)hu);
        spmm_adj<<<adj_grid, BLK, 0, stream>>>(ptrA, packA, (const uint4*)hu,
                                               (const uint4*)ego, (uint4*)next, acc,
                                               l == N_LAYERS - 1 ? 1 : 0);
        unsigned* t = ego; ego = next; next = t;
    }
}

// Round 10
// 450.247 us; speedup vs baseline: 1.0375x; 1.0375x over previous
//
#include <hip/hip_runtime.h>

// LGCN encoder. bf16 propagated embeddings, fp32 acc (= d_out).
// SpMM: one wave per row, 8 lanes x 16B (8 bf16) per gather, 16 nnz in flight.
// CSR build (no O(nnz) global atomics):
//   bucket_count (LDS hist) -> scan_buckets -> bucket_bin (coarse binning,
//   coalesced runs) -> bucket_fused: ONE block per 1024-row bucket (single
//   writer per pack line -> no cross-XCD partial-line write amplification),
//   nontemporal aux reads so streams don't evict the dirty pack window.

constexpr int USER_NUM = 50000;
constexpr int ITEM_NUM = 50000;
constexpr int N_NODES  = USER_NUM + ITEM_NUM;   // 100000
constexpr int EMB      = 64;
constexpr int N_LAYERS = 3;
constexpr int TOTAL    = N_NODES * EMB;         // 6,400,000
constexpr int TOTAL4   = TOTAL / 4;
constexpr int U4       = USER_NUM * EMB / 4;

constexpr int RSHIFT = 10;                      // 1024 rows per bucket
constexpr int RB     = 1 << RSHIFT;
constexpr int KA = (N_NODES + RB - 1) / RB;     // 98
constexpr int KS = (USER_NUM + RB - 1) / RB;    // 49
constexpr int NBIN = 128;                       // histogram bins (>= KA)
constexpr int BCHUNK = 2048;
constexpr int CCH    = 4096;

typedef int v2i __attribute__((ext_vector_type(2)));

__device__ __forceinline__ int   ntl(const int* p)   { return __builtin_nontemporal_load(p); }
__device__ __forceinline__ float ntlf(const float* p){ return __builtin_nontemporal_load(p); }
__device__ __forceinline__ int2  ntl2(const int2* p) {
    v2i v = __builtin_nontemporal_load((const v2i*)p);
    int2 r; r.x = v.x; r.y = v.y; return r;
}

__device__ __forceinline__ unsigned f2bf(float f) {
    unsigned b = __float_as_uint(f);
    return (b + 0x7fffu + ((b >> 16) & 1u)) >> 16;   // RNE
}
__device__ __forceinline__ void bf2x(unsigned u, float& a, float& b) {
    a = __uint_as_float(u << 16);
    b = __uint_as_float(u & 0xffff0000u);
}

__global__ void init_kernel(const float* __restrict__ user_emb,
                            const float* __restrict__ item_emb,
                            unsigned* __restrict__ ego2,
                            float* __restrict__ acc) {
    int i = blockIdx.x * blockDim.x + threadIdx.x;
    if (i >= TOTAL4) return;
    float4 v = (i < U4) ? reinterpret_cast<const float4*>(user_emb)[i]
                        : reinterpret_cast<const float4*>(item_emb)[i - U4];
    reinterpret_cast<float4*>(acc)[i] = v;
    uint2 o;
    o.x = f2bf(v.x) | (f2bf(v.y) << 16);
    o.y = f2bf(v.z) | (f2bf(v.w) << 16);
    reinterpret_cast<uint2*>(ego2)[i] = o;
}

__global__ void zero_small(int* __restrict__ bcntA, int* __restrict__ bcntS) {
    if (threadIdx.x < NBIN) { bcntA[threadIdx.x] = 0; bcntS[threadIdx.x] = 0; }
}

__global__ void __launch_bounds__(256) bucket_count(
    const int* __restrict__ arows, int annz, int nchA, int* __restrict__ bcntA,
    const int* __restrict__ srows, int snnz, int* __restrict__ bcntS)
{
    __shared__ int h[NBIN];
    const int* rows; int nnz; int* bcnt; int chunk;
    if ((int)blockIdx.x < nchA) { rows = arows; nnz = annz; bcnt = bcntA; chunk = blockIdx.x; }
    else                        { rows = srows; nnz = snnz; bcnt = bcntS; chunk = blockIdx.x - nchA; }
    int t = threadIdx.x;
    if (t < NBIN) h[t] = 0;
    __syncthreads();
    int beg = chunk * CCH;
    int end = beg + CCH; if (end > nnz) end = nnz;
    for (int idx = beg + t; idx < end; idx += 256)
        atomicAdd(&h[ntl(rows + idx) >> RSHIFT], 1);
    __syncthreads();
    if (t < NBIN && h[t] > 0) atomicAdd(&bcnt[t], h[t]);
}

__global__ void scan_buckets(const int* __restrict__ bcntA, int* __restrict__ bbaseA,
                             int* __restrict__ tailA, int* __restrict__ ptrA,
                             const int* __restrict__ bcntS, int* __restrict__ bbaseS,
                             int* __restrict__ tailS, int* __restrict__ ptrS)
{
    __shared__ int bufA[KA + 1], bufS[KS + 1];
    int t = threadIdx.x;
    if (t < KA) bufA[t] = bcntA[t];
    if (t < KS) bufS[t] = bcntS[t];
    __syncthreads();
    if (t == 0) {
        int run = 0;
        for (int i = 0; i < KA; ++i) { int c = bufA[i]; bufA[i] = run; run += c; }
        bufA[KA] = run;
        run = 0;
        for (int i = 0; i < KS; ++i) { int c = bufS[i]; bufS[i] = run; run += c; }
        bufS[KS] = run;
    }
    __syncthreads();
    if (t <= KA) { bbaseA[t] = bufA[t]; if (t < KA) tailA[t] = bufA[t]; }
    if (t <= KS) { bbaseS[t] = bufS[t]; if (t < KS) tailS[t] = bufS[t]; }
    if (t == 0) { ptrA[N_NODES] = bufA[KA]; ptrS[USER_NUM] = bufS[KS]; }
}

__global__ void __launch_bounds__(256) bucket_bin(
    const int* __restrict__ arows, const int* __restrict__ acols,
    const float* __restrict__ avals, int annz, int nchA, int* __restrict__ tailA,
    int* __restrict__ auxRA, int* __restrict__ auxCA, float* __restrict__ auxVA,
    const int* __restrict__ srows, const int* __restrict__ scols,
    const float* __restrict__ svals, int snnz, int* __restrict__ tailS,
    int* __restrict__ auxRS, int* __restrict__ auxCS, float* __restrict__ auxVS)
{
    __shared__ int hcnt[NBIN], hoff[NBIN], hcur[NBIN], hbase[NBIN];
    __shared__ int sR[BCHUNK], sC[BCHUNK];
    __shared__ float sV[BCHUNK];
    const int* rows; const int* cols; const float* vals; int nnz; int* tail;
    int* auxR; int* auxC; float* auxV; int chunk;
    if ((int)blockIdx.x < nchA) {
        rows = arows; cols = acols; vals = avals; nnz = annz; tail = tailA;
        auxR = auxRA; auxC = auxCA; auxV = auxVA; chunk = blockIdx.x;
    } else {
        rows = srows; cols = scols; vals = svals; nnz = snnz; tail = tailS;
        auxR = auxRS; auxC = auxCS; auxV = auxVS; chunk = blockIdx.x - nchA;
    }
    int begE = chunk * BCHUNK;
    int cnt = nnz - begE; if (cnt > BCHUNK) cnt = BCHUNK;
    int t = threadIdx.x;
    if (t < NBIN) hcnt[t] = 0;
    __syncthreads();
    int r[8], c[8]; float v[8];
    for (int k = 0; k < 8; ++k) {
        int idx = t + k * 256;
        if (idx < cnt) {
            int e = begE + idx;
            r[k] = ntl(rows + e); c[k] = ntl(cols + e); v[k] = ntlf(vals + e);
            atomicAdd(&hcnt[r[k] >> RSHIFT], 1);
        }
    }
    __syncthreads();
    if (t == 0) {
        int run = 0;
        for (int b = 0; b < NBIN; ++b) { hoff[b] = run; hcur[b] = run; run += hcnt[b]; }
    }
    __syncthreads();
    for (int k = 0; k < 8; ++k) {
        int idx = t + k * 256;
        if (idx < cnt) {
            int b = r[k] >> RSHIFT;
            int pos = atomicAdd(&hcur[b], 1);
            sR[pos] = r[k]; sC[pos] = c[k]; sV[pos] = v[k];
        }
    }
    __syncthreads();
    if (t < NBIN && hcnt[t] > 0) hbase[t] = atomicAdd(&tail[t], hcnt[t]);
    __syncthreads();
    for (int idx = t; idx < cnt; idx += 256) {
        int b = sR[idx] >> RSHIFT;
        int g = hbase[b] + (idx - hoff[b]);
        auxR[g] = sR[idx]; auxC[g] = sC[idx]; auxV[g] = sV[idx];
    }
}

// One block per 1024-row bucket: LDS per-row hist, ladder scan -> ptr[],
// counting-sort scatter. Single block writes each pack line; aux reads are
// nontemporal so the streams don't evict the dirty pack window from L2.
__global__ void __launch_bounds__(1024) bucket_fused(
    const int* __restrict__ auxRA, const int* __restrict__ auxCA,
    const float* __restrict__ auxVA, const int* __restrict__ bbaseA,
    int* __restrict__ ptrA, int2* __restrict__ packA,
    const int* __restrict__ auxRS, const int* __restrict__ auxCS,
    const float* __restrict__ auxVS, const int* __restrict__ bbaseS,
    int* __restrict__ ptrS, int2* __restrict__ packS)
{
    __shared__ int cur[RB];
    __shared__ int s1[1024];
    const int* auxR; const int* auxC; const float* auxV; const int* bbase;
    int* ptr; int2* pack; int b; int n;
    if ((int)blockIdx.x < KA) {
        auxR = auxRA; auxC = auxCA; auxV = auxVA; bbase = bbaseA;
        ptr = ptrA; pack = packA; b = blockIdx.x; n = N_NODES;
    } else {
        auxR = auxRS; auxC = auxCS; auxV = auxVS; bbase = bbaseS;
        ptr = ptrS; pack = packS; b = blockIdx.x - KA; n = USER_NUM;
    }
    int rowbase = b << RSHIFT;
    int nrows = n - rowbase; if (nrows > RB) nrows = RB;
    int segb = bbase[b], sege = bbase[b + 1];
    int t = threadIdx.x;
    cur[t] = 0;
    __syncthreads();
    for (int idx = segb + t; idx < sege; idx += 1024)
        atomicAdd(&cur[ntl(auxR + idx) - rowbase], 1);
    __syncthreads();
    int a0 = cur[t];
    s1[t] = a0;
    __syncthreads();
    for (int off = 1; off < 1024; off <<= 1) {
        int v = (t >= off) ? s1[t - off] : 0;
        __syncthreads();
        s1[t] += v;
        __syncthreads();
    }
    int base = segb + s1[t] - a0;
    cur[t] = base;
    if (t < nrows) ptr[rowbase + t] = base;
    __syncthreads();
    for (int idx = segb + t; idx < sege; idx += 1024) {
        int r = ntl(auxR + idx);
        int pos = atomicAdd(&cur[r - rowbase], 1);
        pack[pos] = make_int2(ntl(auxC + idx), __float_as_int(ntlf(auxV + idx)));
    }
}

__device__ __forceinline__ void gacc(float (&acc)[8], float v, uint4 u) {
    float f0, f1, f2, f3, f4, f5, f6, f7;
    bf2x(u.x, f0, f1); bf2x(u.y, f2, f3); bf2x(u.z, f4, f5); bf2x(u.w, f6, f7);
    acc[0] += v * f0; acc[1] += v * f1; acc[2] += v * f2; acc[3] += v * f3;
    acc[4] += v * f4; acc[5] += v * f5; acc[6] += v * f6; acc[7] += v * f7;
}
__device__ __forceinline__ void reduce8(float (&acc)[8]) {
    for (int m = 8; m < 64; m <<= 1)
        for (int k = 0; k < 8; ++k)
            acc[k] += __shfl_xor(acc[k], m, 64);
}
__device__ __forceinline__ uint4 pack8(const float (&acc)[8]) {
    uint4 o;
    o.x = f2bf(acc[0]) | (f2bf(acc[1]) << 16);
    o.y = f2bf(acc[2]) | (f2bf(acc[3]) << 16);
    o.z = f2bf(acc[4]) | (f2bf(acc[5]) << 16);
    o.w = f2bf(acc[6]) | (f2bf(acc[7]) << 16);
    return o;
}

__global__ void spmm_s(const int* __restrict__ ptr, const int2* __restrict__ pack,
                       const uint4* __restrict__ ego8, uint4* __restrict__ hu8) {
    int r = blockIdx.x * (blockDim.x >> 6) + (threadIdx.x >> 6);
    if (r >= USER_NUM) return;
    int lane = threadIdx.x & 63;
    int g = lane >> 3, li = lane & 7;
    int beg = ptr[r], end = ptr[r + 1];
    float acc[8] = {0, 0, 0, 0, 0, 0, 0, 0};
    int j = beg + g;
    for (; j + 8 < end; j += 16) {
        int2 p0 = ntl2(pack + j);
        int2 p1 = ntl2(pack + j + 8);
        uint4 x0 = ego8[p0.x * 8 + li];
        uint4 x1 = ego8[p1.x * 8 + li];
        gacc(acc, __int_as_float(p0.y), x0);
        gacc(acc, __int_as_float(p1.y), x1);
    }
    if (j < end) {
        int2 p = ntl2(pack + j);
        gacc(acc, __int_as_float(p.y), ego8[p.x * 8 + li]);
    }
    reduce8(acc);
    if (g == 0) {
        uint4 e = ego8[r * 8 + li];
        float f0, f1;
        bf2x(e.x, f0, f1); acc[0] += f0; acc[1] += f1;
        bf2x(e.y, f0, f1); acc[2] += f0; acc[3] += f1;
        bf2x(e.z, f0, f1); acc[4] += f0; acc[5] += f1;
        bf2x(e.w, f0, f1); acc[6] += f0; acc[7] += f1;
        hu8[r * 8 + li] = pack8(acc);
    }
}

__global__ void spmm_adj(const int* __restrict__ ptr, const int2* __restrict__ pack,
                         const uint4* __restrict__ hu8, const uint4* __restrict__ ego8,
                         uint4* __restrict__ next8, float* __restrict__ accbuf, int last) {
    int r = blockIdx.x * (blockDim.x >> 6) + (threadIdx.x >> 6);
    if (r >= N_NODES) return;
    int lane = threadIdx.x & 63;
    int g = lane >> 3, li = lane & 7;
    int beg = ptr[r], end = ptr[r + 1];
    float acc[8] = {0, 0, 0, 0, 0, 0, 0, 0};
    int j = beg + g;
    for (; j + 8 < end; j += 16) {
        int2 p0 = ntl2(pack + j);
        int2 p1 = ntl2(pack + j + 8);
        uint4 x0 = (p0.x < USER_NUM) ? hu8[p0.x * 8 + li] : ego8[p0.x * 8 + li];
        uint4 x1 = (p1.x < USER_NUM) ? hu8[p1.x * 8 + li] : ego8[p1.x * 8 + li];
        gacc(acc, __int_as_float(p0.y), x0);
        gacc(acc, __int_as_float(p1.y), x1);
    }
    if (j < end) {
        int2 p = ntl2(pack + j);
        uint4 x = (p.x < USER_NUM) ? hu8[p.x * 8 + li] : ego8[p.x * 8 + li];
        gacc(acc, __int_as_float(p.y), x);
    }
    reduce8(acc);
    if (g == 0) {
        if (!last) next8[r * 8 + li] = pack8(acc);
        float4* acc4 = reinterpret_cast<float4*>(accbuf);
        int base = r * 16 + li * 2;
        float4 a0 = acc4[base], a1 = acc4[base + 1];
        a0.x += acc[0]; a0.y += acc[1]; a0.z += acc[2]; a0.w += acc[3];
        a1.x += acc[4]; a1.y += acc[5]; a1.z += acc[6]; a1.w += acc[7];
        if (last) {
            a0.x *= 0.25f; a0.y *= 0.25f; a0.z *= 0.25f; a0.w *= 0.25f;
            a1.x *= 0.25f; a1.y *= 0.25f; a1.z *= 0.25f; a1.w *= 0.25f;
        }
        acc4[base] = a0; acc4[base + 1] = a1;
    }
}

extern "C" void kernel_launch(void* const* d_in, const int* in_sizes, int n_in,
                              void* d_out, int out_size, void* d_ws, size_t ws_size,
                              hipStream_t stream) {
    const float* user_emb = (const float*)d_in[0];
    const float* item_emb = (const float*)d_in[1];
    const int*   adj_rows = (const int*)d_in[2];
    const int*   adj_cols = (const int*)d_in[3];
    const float* adj_vals = (const float*)d_in[4];
    const int*   s_rows   = (const int*)d_in[5];
    const int*   s_cols   = (const int*)d_in[6];
    const float* s_vals   = (const float*)d_in[7];
    const int adj_nnz = in_sizes[2];
    const int s_nnz   = in_sizes[5];

    float* acc = (float*)d_out;

    char* p = (char*)d_ws;
    auto alloc = [&](size_t bytes) { void* q = p; p += (bytes + 255) & ~(size_t)255; return q; };
    unsigned* egoA = (unsigned*)alloc((size_t)TOTAL * 2);
    unsigned* egoB = (unsigned*)alloc((size_t)TOTAL * 2);
    unsigned* hu   = (unsigned*)alloc((size_t)USER_NUM * EMB * 2);
    int*   ptrA  = (int*)alloc((size_t)(N_NODES + 1) * 4);
    int2*  packA = (int2*)alloc((size_t)adj_nnz * 8);
    int*   ptrS  = (int*)alloc((size_t)(USER_NUM + 1) * 4);
    int2*  packS = (int2*)alloc((size_t)s_nnz * 8);
    int*   auxRA = (int*)alloc((size_t)adj_nnz * 4);
    int*   auxCA = (int*)alloc((size_t)adj_nnz * 4);
    float* auxVA = (float*)alloc((size_t)adj_nnz * 4);
    int*   auxRS = (int*)alloc((size_t)s_nnz * 4);
    int*   auxCS = (int*)alloc((size_t)s_nnz * 4);
    float* auxVS = (float*)alloc((size_t)s_nnz * 4);
    int*   bcntA = (int*)alloc(NBIN * 4);
    int*   bcntS = (int*)alloc(NBIN * 4);
    int*   bbaseA= (int*)alloc(NBIN * 4);
    int*   bbaseS= (int*)alloc(NBIN * 4);
    int*   tailA = (int*)alloc(NBIN * 4);
    int*   tailS = (int*)alloc(NBIN * 4);

    const int BLK = 256;
    const int ew_grid = (TOTAL4 + BLK - 1) / BLK;
    const int nchA = (adj_nnz + BCHUNK - 1) / BCHUNK;
    const int nchS = (s_nnz + BCHUNK - 1) / BCHUNK;
    const int nccA = (adj_nnz + CCH - 1) / CCH;
    const int nccS = (s_nnz + CCH - 1) / CCH;

    // ---- CSR build ----
    zero_small<<<1, NBIN, 0, stream>>>(bcntA, bcntS);
    bucket_count<<<nccA + nccS, 256, 0, stream>>>(adj_rows, adj_nnz, nccA, bcntA,
                                                  s_rows, s_nnz, bcntS);
    scan_buckets<<<1, NBIN, 0, stream>>>(bcntA, bbaseA, tailA, ptrA,
                                         bcntS, bbaseS, tailS, ptrS);
    bucket_bin<<<nchA + nchS, 256, 0, stream>>>(
        adj_rows, adj_cols, adj_vals, adj_nnz, nchA, tailA, auxRA, auxCA, auxVA,
        s_rows, s_cols, s_vals, s_nnz, tailS, auxRS, auxCS, auxVS);
    bucket_fused<<<KA + KS, 1024, 0, stream>>>(
        auxRA, auxCA, auxVA, bbaseA, ptrA, packA,
        auxRS, auxCS, auxVS, bbaseS, ptrS, packS);

    // ---- init ----
    init_kernel<<<ew_grid, BLK, 0, stream>>>(user_emb, item_emb, egoA, acc);

    unsigned* ego  = egoA;
    unsigned* next = egoB;
    const int s_grid   = (USER_NUM + 3) / 4;
    const int adj_grid = (N_NODES + 3) / 4;

    for (int l = 0; l < N_LAYERS; ++l) {
        spmm_s<<<s_grid, BLK, 0, stream>>>(ptrS, packS, (const uint4*)ego, (uint4*)hu);
        spmm_adj<<<adj_grid, BLK, 0, stream>>>(ptrA, packA, (const uint4*)hu,
                                               (const uint4*)ego, (uint4*)next, acc,
                                               l == N_LAYERS - 1 ? 1 : 0);
        unsigned* t = ego; ego = next; next = t;
    }
}

// Round 11
// 386.779 us; speedup vs baseline: 1.2077x; 1.1641x over previous
//
#include <hip/hip_runtime.h>

// LGCN encoder. bf16 propagated embeddings; acc deferred to one final pass.
// SpMM: one wave per row, 8 lanes x 16B (8 bf16), 16 nnz in flight, cached
// pack loads (L2-resident across layers). CSR build: slot-allocated binning
// (no separate count pass) -> 1-block cnt_scan -> per-bucket fused counting
// sort (single writer per pack line, shuffle-based scan).

constexpr int USER_NUM = 50000;
constexpr int ITEM_NUM = 50000;
constexpr int N_NODES  = USER_NUM + ITEM_NUM;   // 100000
constexpr int EMB      = 64;
constexpr int N_LAYERS = 3;
constexpr int TOTAL    = N_NODES * EMB;         // 6,400,000
constexpr int TOTAL4   = TOTAL / 4;
constexpr int U4       = USER_NUM * EMB / 4;

constexpr int RSHIFT = 10;                      // 1024 rows per bucket
constexpr int RB     = 1 << RSHIFT;
constexpr int KA = (N_NODES + RB - 1) / RB;     // 98
constexpr int KS = (USER_NUM + RB - 1) / RB;    // 49
constexpr int NBIN = 128;
constexpr int BCHUNK = 2048;
constexpr int SLOT   = 17408;                   // bucket slot: mean 16384 + 8 sigma

typedef int v2i __attribute__((ext_vector_type(2)));

__device__ __forceinline__ int   ntl(const int* p)   { return __builtin_nontemporal_load(p); }
__device__ __forceinline__ float ntlf(const float* p){ return __builtin_nontemporal_load(p); }

__device__ __forceinline__ unsigned f2bf(float f) {
    unsigned b = __float_as_uint(f);
    return (b + 0x7fffu + ((b >> 16) & 1u)) >> 16;   // RNE
}
__device__ __forceinline__ void bf2x(unsigned u, float& a, float& b) {
    a = __uint_as_float(u << 16);
    b = __uint_as_float(u & 0xffff0000u);
}

// ego (bf16) = concat inputs (no fp32 acc write — final_sum reads inputs)
__global__ void init_kernel(const float* __restrict__ user_emb,
                            const float* __restrict__ item_emb,
                            unsigned* __restrict__ ego2) {
    int i = blockIdx.x * blockDim.x + threadIdx.x;
    if (i >= TOTAL4) return;
    float4 v = (i < U4) ? reinterpret_cast<const float4*>(user_emb)[i]
                        : reinterpret_cast<const float4*>(item_emb)[i - U4];
    uint2 o;
    o.x = f2bf(v.x) | (f2bf(v.y) << 16);
    o.y = f2bf(v.z) | (f2bf(v.w) << 16);
    reinterpret_cast<uint2*>(ego2)[i] = o;
}

// tails start at fixed per-bucket slot bases
__global__ void init_tails(int* __restrict__ tailA, int* __restrict__ tailS) {
    int t = threadIdx.x;
    if (t < KA) tailA[t] = t * SLOT;
    if (t < KS) tailS[t] = t * SLOT;
}

// LDS-staged binning by row>>RSHIFT; coalesced flush into per-bucket slots.
__global__ void __launch_bounds__(256) bin_alloc(
    const int* __restrict__ arows, const int* __restrict__ acols,
    const float* __restrict__ avals, int annz, int nchA, int* __restrict__ tailA,
    int* __restrict__ auxRA, int* __restrict__ auxCA, float* __restrict__ auxVA,
    const int* __restrict__ srows, const int* __restrict__ scols,
    const float* __restrict__ svals, int snnz, int* __restrict__ tailS,
    int* __restrict__ auxRS, int* __restrict__ auxCS, float* __restrict__ auxVS)
{
    __shared__ int hcnt[NBIN], hoff[NBIN], hcur[NBIN], hbase[NBIN];
    __shared__ int sR[BCHUNK], sC[BCHUNK];
    __shared__ float sV[BCHUNK];
    const int* rows; const int* cols; const float* vals; int nnz; int* tail;
    int* auxR; int* auxC; float* auxV; int chunk;
    if ((int)blockIdx.x < nchA) {
        rows = arows; cols = acols; vals = avals; nnz = annz; tail = tailA;
        auxR = auxRA; auxC = auxCA; auxV = auxVA; chunk = blockIdx.x;
    } else {
        rows = srows; cols = scols; vals = svals; nnz = snnz; tail = tailS;
        auxR = auxRS; auxC = auxCS; auxV = auxVS; chunk = blockIdx.x - nchA;
    }
    int begE = chunk * BCHUNK;
    int cnt = nnz - begE; if (cnt > BCHUNK) cnt = BCHUNK;
    int t = threadIdx.x;
    if (t < NBIN) hcnt[t] = 0;
    __syncthreads();
    int r[8], c[8]; float v[8];
    for (int k = 0; k < 8; ++k) {
        int idx = t + k * 256;
        if (idx < cnt) {
            int e = begE + idx;
            r[k] = ntl(rows + e); c[k] = ntl(cols + e); v[k] = ntlf(vals + e);
            atomicAdd(&hcnt[r[k] >> RSHIFT], 1);
        }
    }
    __syncthreads();
    if (t == 0) {
        int run = 0;
        for (int b = 0; b < NBIN; ++b) { hoff[b] = run; hcur[b] = run; run += hcnt[b]; }
    }
    __syncthreads();
    for (int k = 0; k < 8; ++k) {
        int idx = t + k * 256;
        if (idx < cnt) {
            int b = r[k] >> RSHIFT;
            int pos = atomicAdd(&hcur[b], 1);
            sR[pos] = r[k]; sC[pos] = c[k]; sV[pos] = v[k];
        }
    }
    __syncthreads();
    if (t < NBIN && hcnt[t] > 0) hbase[t] = atomicAdd(&tail[t], hcnt[t]);
    __syncthreads();
    for (int idx = t; idx < cnt; idx += 256) {
        int b = sR[idx] >> RSHIFT;
        int g = hbase[b] + (idx - hoff[b]);
        auxR[g] = sR[idx]; auxC[g] = sC[idx]; auxV[g] = sV[idx];
    }
}

// One block: bucket counts (tail - slotbase) -> exclusive scan -> pack bases.
__global__ void cnt_scan(const int* __restrict__ tailA, int* __restrict__ bbaseA,
                         int* __restrict__ ptrA,
                         const int* __restrict__ tailS, int* __restrict__ bbaseS,
                         int* __restrict__ ptrS) {
    if (threadIdx.x == 0) {
        int run = 0;
        for (int b = 0; b < KA; ++b) { bbaseA[b] = run; run += tailA[b] - b * SLOT; }
        bbaseA[KA] = run; ptrA[N_NODES] = run;
        run = 0;
        for (int b = 0; b < KS; ++b) { bbaseS[b] = run; run += tailS[b] - b * SLOT; }
        bbaseS[KS] = run; ptrS[USER_NUM] = run;
    }
}

// One block per 1024-row bucket: LDS hist, shuffle scan -> ptr[], counting
// sort into this bucket's private pack window (single writer per line).
__global__ void __launch_bounds__(1024) bucket_fused(
    const int* __restrict__ auxRA, const int* __restrict__ auxCA,
    const float* __restrict__ auxVA, const int* __restrict__ tailA,
    const int* __restrict__ bbaseA, int* __restrict__ ptrA, int2* __restrict__ packA,
    const int* __restrict__ auxRS, const int* __restrict__ auxCS,
    const float* __restrict__ auxVS, const int* __restrict__ tailS,
    const int* __restrict__ bbaseS, int* __restrict__ ptrS, int2* __restrict__ packS)
{
    __shared__ int cur[RB];
    __shared__ int wsum[16];
    const int* auxR; const int* auxC; const float* auxV; const int* tail;
    const int* bbase; int* ptr; int2* pack; int b; int n;
    if ((int)blockIdx.x < KA) {
        auxR = auxRA; auxC = auxCA; auxV = auxVA; tail = tailA; bbase = bbaseA;
        ptr = ptrA; pack = packA; b = blockIdx.x; n = N_NODES;
    } else {
        auxR = auxRS; auxC = auxCS; auxV = auxVS; tail = tailS; bbase = bbaseS;
        ptr = ptrS; pack = packS; b = blockIdx.x - KA; n = USER_NUM;
    }
    int rowbase = b << RSHIFT;
    int nrows = n - rowbase; if (nrows > RB) nrows = RB;
    int segb = b * SLOT, sege = tail[b];
    int pbase = bbase[b];
    int t = threadIdx.x;
    cur[t] = 0;
    __syncthreads();
    for (int idx = segb + t; idx < sege; idx += 1024)
        atomicAdd(&cur[ntl(auxR + idx) - rowbase], 1);
    __syncthreads();
    int a0 = cur[t];
    // 64-lane inclusive shuffle scan
    int lane = t & 63, wid = t >> 6;
    int s = a0;
    for (int off = 1; off < 64; off <<= 1) {
        int u = __shfl_up(s, off, 64);
        if (lane >= off) s += u;
    }
    if (lane == 63) wsum[wid] = s;
    __syncthreads();
    if (wid == 0) {
        int w = (lane < 16) ? wsum[lane] : 0;
        for (int off = 1; off < 16; off <<= 1) {
            int u = __shfl_up(w, off, 64);
            if (lane >= off) w += u;
        }
        if (lane < 16) wsum[lane] = w;
    }
    __syncthreads();
    int wbase = (wid > 0) ? wsum[wid - 1] : 0;
    int base = pbase + wbase + s - a0;       // exclusive prefix + pack base
    cur[t] = base;
    if (t < nrows) ptr[rowbase + t] = base;
    __syncthreads();
    for (int idx = segb + t; idx < sege; idx += 1024) {
        int r = ntl(auxR + idx);
        int pos = atomicAdd(&cur[r - rowbase], 1);
        pack[pos] = make_int2(ntl(auxC + idx), __float_as_int(ntlf(auxV + idx)));
    }
}

__device__ __forceinline__ void gacc(float (&acc)[8], float v, uint4 u) {
    float f0, f1, f2, f3, f4, f5, f6, f7;
    bf2x(u.x, f0, f1); bf2x(u.y, f2, f3); bf2x(u.z, f4, f5); bf2x(u.w, f6, f7);
    acc[0] += v * f0; acc[1] += v * f1; acc[2] += v * f2; acc[3] += v * f3;
    acc[4] += v * f4; acc[5] += v * f5; acc[6] += v * f6; acc[7] += v * f7;
}
__device__ __forceinline__ void reduce8(float (&acc)[8]) {
    for (int m = 8; m < 64; m <<= 1)
        for (int k = 0; k < 8; ++k)
            acc[k] += __shfl_xor(acc[k], m, 64);
}
__device__ __forceinline__ uint4 pack8(const float (&acc)[8]) {
    uint4 o;
    o.x = f2bf(acc[0]) | (f2bf(acc[1]) << 16);
    o.y = f2bf(acc[2]) | (f2bf(acc[3]) << 16);
    o.z = f2bf(acc[4]) | (f2bf(acc[5]) << 16);
    o.w = f2bf(acc[6]) | (f2bf(acc[7]) << 16);
    return o;
}

__global__ void spmm_s(const int* __restrict__ ptr, const int2* __restrict__ pack,
                       const uint4* __restrict__ ego8, uint4* __restrict__ hu8) {
    int r = blockIdx.x * (blockDim.x >> 6) + (threadIdx.x >> 6);
    if (r >= USER_NUM) return;
    int lane = threadIdx.x & 63;
    int g = lane >> 3, li = lane & 7;
    int beg = ptr[r], end = ptr[r + 1];
    float acc[8] = {0, 0, 0, 0, 0, 0, 0, 0};
    int j = beg + g;
    for (; j + 8 < end; j += 16) {
        int2 p0 = pack[j];
        int2 p1 = pack[j + 8];
        uint4 x0 = ego8[p0.x * 8 + li];
        uint4 x1 = ego8[p1.x * 8 + li];
        gacc(acc, __int_as_float(p0.y), x0);
        gacc(acc, __int_as_float(p1.y), x1);
    }
    if (j < end) {
        int2 p = pack[j];
        gacc(acc, __int_as_float(p.y), ego8[p.x * 8 + li]);
    }
    reduce8(acc);
    if (g == 0) {
        uint4 e = ego8[r * 8 + li];
        float f0, f1;
        bf2x(e.x, f0, f1); acc[0] += f0; acc[1] += f1;
        bf2x(e.y, f0, f1); acc[2] += f0; acc[3] += f1;
        bf2x(e.z, f0, f1); acc[4] += f0; acc[5] += f1;
        bf2x(e.w, f0, f1); acc[6] += f0; acc[7] += f1;
        hu8[r * 8 + li] = pack8(acc);
    }
}

// next = A*h (h = hu for user cols, ego for item cols). No acc RMW here.
__global__ void spmm_adj(const int* __restrict__ ptr, const int2* __restrict__ pack,
                         const uint4* __restrict__ hu8, const uint4* __restrict__ ego8,
                         uint4* __restrict__ next8) {
    int r = blockIdx.x * (blockDim.x >> 6) + (threadIdx.x >> 6);
    if (r >= N_NODES) return;
    int lane = threadIdx.x & 63;
    int g = lane >> 3, li = lane & 7;
    int beg = ptr[r], end = ptr[r + 1];
    float acc[8] = {0, 0, 0, 0, 0, 0, 0, 0};
    int j = beg + g;
    for (; j + 8 < end; j += 16) {
        int2 p0 = pack[j];
        int2 p1 = pack[j + 8];
        uint4 x0 = (p0.x < USER_NUM) ? hu8[p0.x * 8 + li] : ego8[p0.x * 8 + li];
        uint4 x1 = (p1.x < USER_NUM) ? hu8[p1.x * 8 + li] : ego8[p1.x * 8 + li];
        gacc(acc, __int_as_float(p0.y), x0);
        gacc(acc, __int_as_float(p1.y), x1);
    }
    if (j < end) {
        int2 p = pack[j];
        uint4 x = (p.x < USER_NUM) ? hu8[p.x * 8 + li] : ego8[p.x * 8 + li];
        gacc(acc, __int_as_float(p.y), x);
    }
    reduce8(acc);
    if (g == 0) next8[r * 8 + li] = pack8(acc);
}

// acc = (inputs_fp32 + e1 + e2 + e3) * 0.25
__global__ void final_sum(const float* __restrict__ user_emb,
                          const float* __restrict__ item_emb,
                          const uint2* __restrict__ e1, const uint2* __restrict__ e2,
                          const uint2* __restrict__ e3, float* __restrict__ acc) {
    int i = blockIdx.x * blockDim.x + threadIdx.x;
    if (i >= TOTAL4) return;
    float4 v = (i < U4) ? reinterpret_cast<const float4*>(user_emb)[i]
                        : reinterpret_cast<const float4*>(item_emb)[i - U4];
    uint2 a = e1[i], b = e2[i], c = e3[i];
    float f0, f1;
    bf2x(a.x, f0, f1); v.x += f0; v.y += f1;
    bf2x(a.y, f0, f1); v.z += f0; v.w += f1;
    bf2x(b.x, f0, f1); v.x += f0; v.y += f1;
    bf2x(b.y, f0, f1); v.z += f0; v.w += f1;
    bf2x(c.x, f0, f1); v.x += f0; v.y += f1;
    bf2x(c.y, f0, f1); v.z += f0; v.w += f1;
    v.x *= 0.25f; v.y *= 0.25f; v.z *= 0.25f; v.w *= 0.25f;
    reinterpret_cast<float4*>(acc)[i] = v;
}

extern "C" void kernel_launch(void* const* d_in, const int* in_sizes, int n_in,
                              void* d_out, int out_size, void* d_ws, size_t ws_size,
                              hipStream_t stream) {
    const float* user_emb = (const float*)d_in[0];
    const float* item_emb = (const float*)d_in[1];
    const int*   adj_rows = (const int*)d_in[2];
    const int*   adj_cols = (const int*)d_in[3];
    const float* adj_vals = (const float*)d_in[4];
    const int*   s_rows   = (const int*)d_in[5];
    const int*   s_cols   = (const int*)d_in[6];
    const float* s_vals   = (const float*)d_in[7];
    const int adj_nnz = in_sizes[2];
    const int s_nnz   = in_sizes[5];

    float* acc = (float*)d_out;

    char* p = (char*)d_ws;
    auto alloc = [&](size_t bytes) { void* q = p; p += (bytes + 255) & ~(size_t)255; return q; };
    unsigned* egoA = (unsigned*)alloc((size_t)TOTAL * 2);
    unsigned* egoB = (unsigned*)alloc((size_t)TOTAL * 2);
    unsigned* egoC = (unsigned*)alloc((size_t)TOTAL * 2);
    unsigned* hu   = (unsigned*)alloc((size_t)USER_NUM * EMB * 2);
    int*   ptrA  = (int*)alloc((size_t)(N_NODES + 1) * 4);
    int2*  packA = (int2*)alloc((size_t)adj_nnz * 8);
    int*   ptrS  = (int*)alloc((size_t)(USER_NUM + 1) * 4);
    int2*  packS = (int2*)alloc((size_t)s_nnz * 8);
    int*   auxRA = (int*)alloc((size_t)KA * SLOT * 4);
    int*   auxCA = (int*)alloc((size_t)KA * SLOT * 4);
    float* auxVA = (float*)alloc((size_t)KA * SLOT * 4);
    int*   auxRS = (int*)alloc((size_t)KS * SLOT * 4);
    int*   auxCS = (int*)alloc((size_t)KS * SLOT * 4);
    float* auxVS = (float*)alloc((size_t)KS * SLOT * 4);
    int*   tailA = (int*)alloc(NBIN * 4);
    int*   tailS = (int*)alloc(NBIN * 4);
    int*   bbaseA= (int*)alloc(NBIN * 4);
    int*   bbaseS= (int*)alloc(NBIN * 4);

    const int BLK = 256;
    const int ew_grid = (TOTAL4 + BLK - 1) / BLK;
    const int nchA = (adj_nnz + BCHUNK - 1) / BCHUNK;
    const int nchS = (s_nnz + BCHUNK - 1) / BCHUNK;

    // ---- CSR build ----
    init_tails<<<1, NBIN, 0, stream>>>(tailA, tailS);
    bin_alloc<<<nchA + nchS, 256, 0, stream>>>(
        adj_rows, adj_cols, adj_vals, adj_nnz, nchA, tailA, auxRA, auxCA, auxVA,
        s_rows, s_cols, s_vals, s_nnz, tailS, auxRS, auxCS, auxVS);
    cnt_scan<<<1, 64, 0, stream>>>(tailA, bbaseA, ptrA, tailS, bbaseS, ptrS);
    bucket_fused<<<KA + KS, 1024, 0, stream>>>(
        auxRA, auxCA, auxVA, tailA, bbaseA, ptrA, packA,
        auxRS, auxCS, auxVS, tailS, bbaseS, ptrS, packS);

    // ---- init ego ----
    init_kernel<<<ew_grid, BLK, 0, stream>>>(user_emb, item_emb, egoA);

    unsigned* bufs[3] = {egoA, egoB, egoC};
    const int s_grid   = (USER_NUM + 3) / 4;
    const int adj_grid = (N_NODES + 3) / 4;

    for (int l = 0; l < N_LAYERS; ++l) {
        unsigned* in  = bufs[l % 3];
        unsigned* out = bufs[(l + 1) % 3];
        spmm_s<<<s_grid, BLK, 0, stream>>>(ptrS, packS, (const uint4*)in, (uint4*)hu);
        spmm_adj<<<adj_grid, BLK, 0, stream>>>(ptrA, packA, (const uint4*)hu,
                                               (const uint4*)in, (uint4*)out);
    }
    // e1=egoB, e2=egoC, e3=egoA
    final_sum<<<ew_grid, BLK, 0, stream>>>(user_emb, item_emb,
                                           (const uint2*)egoB, (const uint2*)egoC,
                                           (const uint2*)egoA, acc);
}